// Round 11
// baseline (763.116 us; speedup 1.0000x reference)
//
#include <hip/hip_runtime.h>

typedef short bf16x8 __attribute__((ext_vector_type(8)));
typedef short bf16x4 __attribute__((ext_vector_type(4)));
typedef float f32x4  __attribute__((ext_vector_type(4)));

static constexpr int Nd    = 50000;
static constexpr int Cd    = 256;
static constexpr int Wd    = 256;
static constexpr int NWd   = 196;        // windows per batch
static constexpr int NB2   = 392;        // total (batch,window) pairs
static constexpr int NROWS = 100000;     // valid global rows

#define DEV static __device__ __forceinline__

DEV short f2bf(float f) {
  unsigned u = __float_as_uint(f);
  u += 0x7fffu + ((u >> 16) & 1u);   // round-to-nearest-even
  return (short)(u >> 16);
}

DEV bf16x8 ldfrag(const short* p) {
  // two-half k layout: k = 4*(lane>>4)+j and k = 16 + 4*(lane>>4)+j.
  // Any k-permutation error cancels because A and B use the same rule.
  bf16x4 a = *(const bf16x4*)(p);
  bf16x4 b = *(const bf16x4*)(p + 16);
  return __builtin_shufflevector(a, b, 0, 1, 2, 3, 4, 5, 6, 7);
}

DEV f32x4 mfma16(bf16x8 a, bf16x8 b, f32x4 c) {
  return __builtin_amdgcn_mfma_f32_16x16x32_bf16(a, b, c, 0, 0, 0);
}

DEV bf16x8 pack8(float4 lo, float4 hi) {
  bf16x8 r;
  r[0] = f2bf(lo.x); r[1] = f2bf(lo.y); r[2] = f2bf(lo.z); r[3] = f2bf(lo.w);
  r[4] = f2bf(hi.x); r[5] = f2bf(hi.y); r[6] = f2bf(hi.z); r[7] = f2bf(hi.w);
  return r;
}

// ---------------------------------------------------------------------------
// K1: one block per (head, batch-window). QKV proj for 96 cols + attention.
// blk = h*392 + wb so the 8 head-blocks of a window share blk%8 (same XCD
// under round-robin) -> x window served from one L2.
// A-fragments (x) are loaded straight from global (L2/L3-hot), pipelined one
// kc ahead; only W needs LDS staging in the K-loop.
// ---------------------------------------------------------------------------
__global__ __launch_bounds__(512, 4)
void wattn_qkv_attn(const float* __restrict__ x,
                    const float* __restrict__ qkv_w,
                    const float* __restrict__ qkv_b,
                    float* __restrict__ out,
                    short* __restrict__ obf, int useWs)
{
  // LDS (shorts): Qs/Ps @0 [256][36], Wt @9216 [96][36],
  //               Ks @12672 [256][36], Vt @21888 [32][260]  => 60416 B
  __shared__ short lds[30208];
  short (*Qs)[36]  = (short(*)[36]) (lds);
  short (*Ps)[36]  = (short(*)[36]) (lds);
  short (*Wt)[36]  = (short(*)[36]) (lds + 9216);
  short (*Ks)[36]  = (short(*)[36]) (lds + 12672);
  short (*Vt)[260] = (short(*)[260])(lds + 21888);

  const int blk = blockIdx.x;
  const int h   = blk / NB2;
  const int wb  = blk % NB2;
  const int b   = wb / NWd;
  const int w   = wb % NWd;
  const int n0  = w * Wd;
  const int valid = (Nd - n0 < Wd) ? (Nd - n0) : Wd;

  const float* xw = x + ((size_t)b * Nd + n0) * Cd;
  const size_t gro = (size_t)b * Nd + n0;          // global row offset

  const int tid  = threadIdx.x;
  const int wid  = tid >> 6;
  const int lane = tid & 63;
  const int l15  = lane & 15;
  const int l4   = lane >> 4;
  const int rb   = wid * 32;
  const float scale = 0.1767766952966369f;  // 1/sqrt(32)

  // A-fragment loader: rows rb+rowofs+l15, k-chunk kc (two 16-B halves)
  auto loadA = [&](int kc, int rowofs) -> bf16x8 {
    int row = rb + rowofs + l15;
    float4 lo = make_float4(0.f, 0.f, 0.f, 0.f), hi = lo;
    if (row < valid) {
      const float* p = &xw[(size_t)row * Cd + kc * 32 + l4 * 4];
      lo = *(const float4*)p;
      hi = *(const float4*)(p + 16);
    }
    return pack8(lo, hi);
  };

  // ---------------- QKV GEMM: [256 rows] x [96 cols], K=256 ----------------
  f32x4 acc[2][6];
#pragma unroll
  for (int i = 0; i < 2; ++i)
#pragma unroll
    for (int j = 0; j < 6; ++j) acc[i][j] = (f32x4){0.f, 0.f, 0.f, 0.f};

  bf16x8 a0 = loadA(0, 0), a1 = loadA(0, 16);

  for (int kc = 0; kc < 8; ++kc) {
    __syncthreads();   // Wt readers of prev iter done
    // stage W chunk transposed: sections Q,K,V each [32 k][32 n]
#pragma unroll
    for (int i = 0; i < 6; ++i) {
      int idx = tid + i * 512;          // 0..3071
      int sec = idx >> 10;              // 0=Q 1=K 2=V
      int k   = (idx >> 5) & 31;
      int n   = idx & 31;
      float v = qkv_w[(size_t)(kc * 32 + k) * (3 * Cd) + sec * Cd + h * 32 + n];
      Wt[sec * 32 + n][k] = f2bf(v);
    }
    // prefetch next kc's A-frags (overlaps barrier + LDS reads)
    bf16x8 na0 = a0, na1 = a1;
    if (kc < 7) { na0 = loadA(kc + 1, 0); na1 = loadA(kc + 1, 16); }
    __syncthreads();
#pragma unroll
    for (int fc = 0; fc < 6; ++fc) {
      bf16x8 bb = ldfrag(&Wt[fc * 16 + l15][l4 * 4]);
      acc[0][fc] = mfma16(a0, bb, acc[0][fc]);
      acc[1][fc] = mfma16(a1, bb, acc[1][fc]);
    }
    a0 = na0; a1 = na1;
  }

  // ---------------- write Q,K,V to LDS ------------------------------------
  // C/D layout: col = lane&15, row = 4*(lane>>4)+reg (HW-verified).
#pragma unroll
  for (int fc = 0; fc < 6; ++fc) {
    int sec  = fc >> 1;
    int colh = (fc & 1) * 16 + l15;
    float bias = qkv_b[sec * Cd + h * 32 + colh];
#pragma unroll
    for (int fr = 0; fr < 2; ++fr) {
      int row0 = rb + fr * 16 + l4 * 4;
      f32x4 v = acc[fr][fc];
      if (sec == 0) {
#pragma unroll
        for (int r = 0; r < 4; ++r) Qs[row0 + r][colh] = f2bf((v[r] + bias) * scale);
      } else if (sec == 1) {
#pragma unroll
        for (int r = 0; r < 4; ++r) Ks[row0 + r][colh] = f2bf(v[r] + bias);
      } else {
        bf16x4 s4 = { f2bf(v[0] + bias), f2bf(v[1] + bias),
                      f2bf(v[2] + bias), f2bf(v[3] + bias) };
        *(bf16x4*)&Vt[colh][row0] = s4;
      }
    }
  }
  __syncthreads();   // K,V visible to all waves

  // ---------------- S = Q K^T ----------------------------------------------
  bf16x8 qa0 = ldfrag(&Qs[rb + l15][l4 * 4]);
  bf16x8 qa1 = ldfrag(&Qs[rb + 16 + l15][l4 * 4]);
  f32x4 s[2][16];
#pragma unroll
  for (int fc = 0; fc < 16; ++fc) {
    bf16x8 kb = ldfrag(&Ks[fc * 16 + l15][l4 * 4]);
    f32x4 z = (f32x4){0.f, 0.f, 0.f, 0.f};
    s[0][fc] = mfma16(qa0, kb, z);
    s[1][fc] = mfma16(qa1, kb, z);
  }

  // ---------------- softmax (deferred normalization) -----------------------
  float sminv[2][4];
#pragma unroll
  for (int fr = 0; fr < 2; ++fr)
#pragma unroll
    for (int r = 0; r < 4; ++r) {
      float m = -1e30f;
#pragma unroll
      for (int fc = 0; fc < 16; ++fc) m = fmaxf(m, s[fr][fc][r]);
#pragma unroll
      for (int d = 1; d < 16; d <<= 1) m = fmaxf(m, __shfl_xor(m, d));
      float t = 0.f;
#pragma unroll
      for (int fc = 0; fc < 16; ++fc) {
        float e = __expf(s[fr][fc][r] - m);
        s[fr][fc][r] = e;
        t += e;
      }
#pragma unroll
      for (int d = 1; d < 16; d <<= 1) t += __shfl_xor(t, d);
      sminv[fr][r] = 1.f / t;
    }

  // ---------------- O = P V (P via wave-private LDS rows) ------------------
  f32x4 o[2][2];
  o[0][0] = o[0][1] = o[1][0] = o[1][1] = (f32x4){0.f, 0.f, 0.f, 0.f};
#pragma unroll
  for (int c = 0; c < 8; ++c) {
#pragma unroll
    for (int fr = 0; fr < 2; ++fr)
#pragma unroll
      for (int fc2 = 0; fc2 < 2; ++fc2) {
        f32x4 v = s[fr][c * 2 + fc2];
        int row0 = rb + fr * 16 + l4 * 4;
#pragma unroll
        for (int r = 0; r < 4; ++r)
          Ps[row0 + r][fc2 * 16 + l15] = f2bf(v[r]);
      }
    bf16x8 pa0 = ldfrag(&Ps[rb + l15][l4 * 4]);
    bf16x8 pa1 = ldfrag(&Ps[rb + 16 + l15][l4 * 4]);
#pragma unroll
    for (int fc2 = 0; fc2 < 2; ++fc2) {
      bf16x8 vb = ldfrag(&Vt[fc2 * 16 + l15][c * 32 + l4 * 4]);
      o[0][fc2] = mfma16(pa0, vb, o[0][fc2]);
      o[1][fc2] = mfma16(pa1, vb, o[1][fc2]);
    }
  }

  // ---------------- write O (normalized) -----------------------------------
#pragma unroll
  for (int fr = 0; fr < 2; ++fr)
#pragma unroll
    for (int fc2 = 0; fc2 < 2; ++fc2)
#pragma unroll
      for (int r = 0; r < 4; ++r) {
        int row = rb + fr * 16 + l4 * 4 + r;
        if (row < valid) {
          float v = o[fr][fc2][r] * sminv[fr][r];
          int col = h * 32 + fc2 * 16 + l15;
          if (useWs) obf[(gro + row) * Cd + col] = f2bf(v);
          else       out[(gro + row) * Cd + col] = v;
        }
      }
}

// ---------------------------------------------------------------------------
// K2: output projection, tile M=128, N=256, K=256. Wt chunk (32k x 256n)
// re-staged per kc with double barrier (R0-proven pattern — the R10 failure
// was a "stage-once" Wt that overflowed [256][36] and ignored kc on read).
// O staged wave-private. In-place safe on the fp32 path: all global reads
// precede all writes; each wave touches only its own 16 rows.
// ---------------------------------------------------------------------------
__global__ __launch_bounds__(512, 4)
void wattn_proj2(const float* __restrict__ o_f32,
                 const short* __restrict__ o_bf,
                 const float* __restrict__ proj_w,
                 const float* __restrict__ proj_b,
                 float* __restrict__ out, int useWs)
{
  __shared__ short Os[128][36];   //  9216 B
  __shared__ short Wt[256][36];   // 18432 B (per-kc chunk: n rows, k 0..31)

  const int r0   = blockIdx.x * 128;
  const int tid  = threadIdx.x;
  const int wid  = tid >> 6;
  const int lane = tid & 63;
  const int l15  = lane & 15;
  const int l4   = lane >> 4;

  f32x4 acc[16];
#pragma unroll
  for (int j = 0; j < 16; ++j) acc[j] = (f32x4){0.f, 0.f, 0.f, 0.f};

  const int srow = wid * 16 + (lane >> 2);  // wave-private staging row
  const int sq   = (lane & 3) * 8;          // 8 cols per lane
  const int grow = r0 + srow;

  for (int kc = 0; kc < 8; ++kc) {
    __syncthreads();   // Wt/Os readers of prev iter done
    // stage Wt chunk: global k = kc*32 + k, all 256 n (coalesced over n)
#pragma unroll
    for (int i = 0; i < 16; ++i) {
      int idx = tid + i * 512;          // 0..8191
      int k = idx >> 8;                 // 0..31
      int n = idx & 255;
      Wt[n][k] = f2bf(proj_w[(size_t)(kc * 32 + k) * Cd + n]);
    }
    // stage own O rows (wave-private: 16 rows x 32 k per wave)
    if (useWs) {
      bf16x8 v = {0,0,0,0,0,0,0,0};
      if (grow < NROWS) v = *(const bf16x8*)&o_bf[(size_t)grow * Cd + kc * 32 + sq];
      *(bf16x4*)&Os[srow][sq]     = __builtin_shufflevector(v, v, 0, 1, 2, 3);
      *(bf16x4*)&Os[srow][sq + 4] = __builtin_shufflevector(v, v, 4, 5, 6, 7);
    } else {
      float4 lo = make_float4(0.f, 0.f, 0.f, 0.f), hi = lo;
      if (grow < NROWS) {
        const float* p = &o_f32[(size_t)grow * Cd + kc * 32 + sq];
        lo = *(const float4*)p;
        hi = *(const float4*)(p + 4);
      }
      bf16x4 s0 = { f2bf(lo.x), f2bf(lo.y), f2bf(lo.z), f2bf(lo.w) };
      bf16x4 s1 = { f2bf(hi.x), f2bf(hi.y), f2bf(hi.z), f2bf(hi.w) };
      *(bf16x4*)&Os[srow][sq]     = s0;
      *(bf16x4*)&Os[srow][sq + 4] = s1;
    }
    __syncthreads();
    bf16x8 a = ldfrag(&Os[wid * 16 + l15][l4 * 4]);   // own wave's rows
#pragma unroll
    for (int fc = 0; fc < 16; ++fc) {
      bf16x8 bb = ldfrag(&Wt[fc * 16 + l15][l4 * 4]);
      acc[fc] = mfma16(a, bb, acc[fc]);
    }
  }

#pragma unroll
  for (int fc = 0; fc < 16; ++fc) {
    float bias = proj_b[fc * 16 + l15];
#pragma unroll
    for (int r = 0; r < 4; ++r) {
      int row = r0 + wid * 16 + l4 * 4 + r;
      if (row < NROWS)
        out[(size_t)row * Cd + fc * 16 + l15] = acc[fc][r] + bias;
    }
  }
}

extern "C" void kernel_launch(void* const* d_in, const int* in_sizes, int n_in,
                              void* d_out, int out_size, void* d_ws, size_t ws_size,
                              hipStream_t stream) {
  const float* x      = (const float*)d_in[0];
  const float* qkv_w  = (const float*)d_in[1];
  const float* qkv_b  = (const float*)d_in[2];
  const float* proj_w = (const float*)d_in[3];
  const float* proj_b = (const float*)d_in[4];
  float* out = (float*)d_out;

  const size_t oBytes = (size_t)NROWS * Cd * sizeof(short);
  int useWs = (d_ws != nullptr && ws_size >= oBytes) ? 1 : 0;
  short* obf = (short*)d_ws;

  wattn_qkv_attn<<<dim3(8 * NB2), dim3(512), 0, stream>>>(x, qkv_w, qkv_b, out, obf, useWs);
  wattn_proj2<<<dim3((NROWS + 127) / 128), dim3(512), 0, stream>>>(out, obf, proj_w, proj_b, out, useWs);
}